// Round 1
// baseline (235.489 us; speedup 1.0000x reference)
//
#include <hip/hip_runtime.h>
#include <hip/hip_bf16.h>

// Fused GATConv + proj + LayerNorm + ReLU for N=50000, E=800000, F_IN=128, H=4, C=16, D=128.
// Pipeline:
//   k_xw    : xp = x@W  (per-head features) + a_src/a_dst attention logits per node
//   k_hist  : deg[dst]++ per edge
//   k_scan* : exclusive prefix sum -> row_ptr (CSR by destination)
//   k_fill  : scatter src indices into CSR slots
//   k_agg   : per-node segment softmax + weighted aggregation + proj + LN + ReLU

#define LEAKY(x) ((x) > 0.f ? (x) : 0.2f * (x))

__global__ __launch_bounds__(256) void k_xw(
    const float* __restrict__ x, const float* __restrict__ W,
    const float* __restrict__ att_src, const float* __restrict__ att_dst,
    float* __restrict__ xp, float* __restrict__ a_src, float* __restrict__ a_dst,
    int n_nodes)
{
    __shared__ float Wl[128][64];   // 32 KB
    __shared__ float xl[16][128];   // 8 KB
    __shared__ float asl[64], adl[64];
    int t = threadIdx.x;
    for (int idx = t; idx < 128 * 64; idx += 256) Wl[idx >> 6][idx & 63] = W[idx];
    if (t < 64) { asl[t] = att_src[t]; adl[t] = att_dst[t]; }
    int nbase = blockIdx.x * 16;
    for (int idx = t; idx < 16 * 128; idx += 256) {
        int r = idx >> 7, k = idx & 127;
        int n = nbase + r;
        xl[r][k] = (n < n_nodes) ? x[(size_t)n * 128 + k] : 0.f;
    }
    __syncthreads();
    int w = t >> 6, lane = t & 63;
    float acc[4] = {0.f, 0.f, 0.f, 0.f};
    for (int k = 0; k < 128; k++) {
        float wv = Wl[k][lane];
        acc[0] += xl[w * 4 + 0][k] * wv;
        acc[1] += xl[w * 4 + 1][k] * wv;
        acc[2] += xl[w * 4 + 2][k] * wv;
        acc[3] += xl[w * 4 + 3][k] * wv;
    }
    int h = lane >> 4;
    for (int i = 0; i < 4; i++) {
        int n = nbase + w * 4 + i;
        if (n >= n_nodes) break;
        xp[(size_t)n * 64 + lane] = acc[i];
        float ts = acc[i] * asl[lane];
        float td = acc[i] * adl[lane];
        for (int off = 8; off; off >>= 1) {
            ts += __shfl_xor(ts, off);
            td += __shfl_xor(td, off);
        }
        if ((lane & 15) == 0) { a_src[n * 4 + h] = ts; a_dst[n * 4 + h] = td; }
    }
}

__global__ __launch_bounds__(256) void k_hist(const int* __restrict__ dst, int* __restrict__ deg, int E)
{
    int e = blockIdx.x * 256 + threadIdx.x;
    if (e < E) atomicAdd(&deg[dst[e]], 1);
}

__global__ __launch_bounds__(256) void k_scan1(const int* __restrict__ deg, int* __restrict__ row_ptr,
                                               int* __restrict__ partial, int n)
{
    __shared__ int sh[256];
    int t = threadIdx.x, g = blockIdx.x * 256 + t;
    int v = (g < n) ? deg[g] : 0;
    sh[t] = v; __syncthreads();
    for (int off = 1; off < 256; off <<= 1) {
        int u = (t >= off) ? sh[t - off] : 0;
        __syncthreads();
        sh[t] += u;
        __syncthreads();
    }
    if (g < n) row_ptr[g] = sh[t];          // local inclusive scan (temp)
    if (t == 255) partial[blockIdx.x] = sh[255];
}

__global__ __launch_bounds__(256) void k_scan2(int* __restrict__ partial, int nblk)
{
    __shared__ int sh[256];
    int t = threadIdx.x;
    int v = (t < nblk) ? partial[t] : 0;
    sh[t] = v; __syncthreads();
    for (int off = 1; off < 256; off <<= 1) {
        int u = (t >= off) ? sh[t - off] : 0;
        __syncthreads();
        sh[t] += u;
        __syncthreads();
    }
    if (t < nblk) partial[t] = sh[t] - v;   // exclusive block offsets
}

__global__ __launch_bounds__(256) void k_scan3(const int* __restrict__ deg, int* __restrict__ row_ptr,
                                               int* __restrict__ cursor, const int* __restrict__ partial,
                                               int n, int E_total)
{
    int g = blockIdx.x * 256 + threadIdx.x;
    if (g < n) {
        int rp = partial[blockIdx.x] + row_ptr[g] - deg[g];   // exclusive global
        row_ptr[g] = rp;
        cursor[g] = rp;
    }
    if (g == 0) row_ptr[n] = E_total;
}

__global__ __launch_bounds__(256) void k_fill(const int* __restrict__ src, const int* __restrict__ dst,
                                              int* __restrict__ cursor, int* __restrict__ colsrc, int E)
{
    int e = blockIdx.x * 256 + threadIdx.x;
    if (e < E) {
        int d = dst[e];
        int p = atomicAdd(&cursor[d], 1);
        colsrc[p] = src[e];
    }
}

__global__ __launch_bounds__(256) void k_agg(
    const float* __restrict__ xp, const float* __restrict__ a_src, const float* __restrict__ a_dst,
    const int* __restrict__ row_ptr, const int* __restrict__ colsrc,
    const float* __restrict__ bias, const float* __restrict__ proj_w, const float* __restrict__ proj_b,
    const float* __restrict__ gamma, const float* __restrict__ beta,
    float* __restrict__ out, int n_nodes)
{
    __shared__ float pwT[64][129];     // transposed proj_w, padded: 33 KB
    __shared__ float rowbuf[16][64];   // aggregated rows (+bias): 4 KB
    __shared__ int   sstage[4][64];    // per-wave staged src indices: 1 KB
    int t = threadIdx.x;
    for (int idx = t; idx < 128 * 64; idx += 256) {
        int d = idx >> 6, j = idx & 63;
        pwT[j][d] = proj_w[idx];       // conflict-free: bank = (129*j + d) % 32 varies with j
    }
    __syncthreads();
    int w = t >> 6, lane = t & 63, h = lane >> 4;
    int nbase = blockIdx.x * 16 + w * 4;

    for (int i = 0; i < 4; i++) {
        int n = nbase + i;
        if (n >= n_nodes) continue;
        int rp0 = row_ptr[n], rp1 = row_ptr[n + 1];
        float adst = a_dst[n * 4 + h];
        // pass 1: per-head max of leaky_relu(a_src[s] + a_dst[n])
        float mx = -1e30f;
        for (int base = rp0; base < rp1; base += 64) {
            int cnt = rp1 - base; if (cnt > 64) cnt = 64;
            if (lane < cnt) sstage[w][lane] = colsrc[base + lane];
            // wave-lockstep: same-wave LDS write->read needs no barrier
            for (int q = 0; q < 4; q++) {
                int j = (lane & 15) + q * 16;
                if (j < cnt) {
                    int s = sstage[w][j];
                    float e = a_src[s * 4 + h] + adst;
                    e = LEAKY(e);
                    mx = fmaxf(mx, e);
                }
            }
        }
        for (int off = 8; off; off >>= 1) mx = fmaxf(mx, __shfl_xor(mx, off));
        // pass 2: weighted accumulate
        float acc = 0.f, den = 0.f;
        for (int base = rp0; base < rp1; base += 64) {
            int cnt = rp1 - base; if (cnt > 64) cnt = 64;
            if (lane < cnt) sstage[w][lane] = colsrc[base + lane];
            for (int j = 0; j < cnt; j++) {
                int s = sstage[w][j];
                float e = a_src[s * 4 + h] + adst;
                e = LEAKY(e);
                float p = __expf(e - mx);
                den += p;
                acc += p * xp[(size_t)s * 64 + lane];
            }
        }
        rowbuf[w * 4 + i][lane] = acc / (den + 1e-16f) + bias[lane];
    }
    // per-wave projection of its own 4 rows: y[d] = sum_j pw[d][j]*row[j] + proj_b[d]
    float y0[4], y1[4];
    for (int i = 0; i < 4; i++) { y0[i] = proj_b[lane]; y1[i] = proj_b[lane + 64]; }
    int w4 = w * 4;
    for (int j = 0; j < 64; j++) {
        float p0 = pwT[j][lane], p1 = pwT[j][lane + 64];
        float r0 = rowbuf[w4 + 0][j], r1 = rowbuf[w4 + 1][j];
        float r2 = rowbuf[w4 + 2][j], r3 = rowbuf[w4 + 3][j];
        y0[0] += r0 * p0; y1[0] += r0 * p1;
        y0[1] += r1 * p0; y1[1] += r1 * p1;
        y0[2] += r2 * p0; y1[2] += r2 * p1;
        y0[3] += r3 * p0; y1[3] += r3 * p1;
    }
    float g0 = gamma[lane], g1 = gamma[lane + 64];
    float b0 = beta[lane],  b1 = beta[lane + 64];
    for (int i = 0; i < 4; i++) {
        int n = nbase + i;
        if (n >= n_nodes) continue;
        float v0 = y0[i], v1 = y1[i];
        float S = v0 + v1, Q = v0 * v0 + v1 * v1;
        for (int off = 32; off; off >>= 1) {
            S += __shfl_xor(S, off);
            Q += __shfl_xor(Q, off);
        }
        float mu  = S * (1.f / 128.f);
        float var = Q * (1.f / 128.f) - mu * mu;
        float inv = rsqrtf(var + 1e-5f);
        float o0 = fmaxf((v0 - mu) * inv * g0 + b0, 0.f);
        float o1 = fmaxf((v1 - mu) * inv * g1 + b1, 0.f);
        out[(size_t)n * 128 + lane]      = o0;
        out[(size_t)n * 128 + lane + 64] = o1;
    }
}

extern "C" void kernel_launch(void* const* d_in, const int* in_sizes, int n_in,
                              void* d_out, int out_size, void* d_ws, size_t ws_size,
                              hipStream_t stream)
{
    const float* x       = (const float*)d_in[0];
    const int*   ei      = (const int*)  d_in[1];
    const float* W       = (const float*)d_in[2];
    const float* att_src = (const float*)d_in[3];
    const float* att_dst = (const float*)d_in[4];
    const float* bias    = (const float*)d_in[5];
    const float* proj_w  = (const float*)d_in[6];
    const float* proj_b  = (const float*)d_in[7];
    const float* gamma   = (const float*)d_in[8];
    const float* beta    = (const float*)d_in[9];

    int N = in_sizes[0] / 128;
    int E = in_sizes[1] / 2;
    const int* srcIdx = ei;
    const int* dstIdx = ei + E;

    char* ws = (char*)d_ws;
    float* xp      = (float*)ws; ws += (size_t)N * 64 * 4;
    float* a_src   = (float*)ws; ws += (size_t)N * 4 * 4;
    float* a_dst   = (float*)ws; ws += (size_t)N * 4 * 4;
    int*   deg     = (int*)ws;   ws += (size_t)N * 4;
    int*   row_ptr = (int*)ws;   ws += (size_t)(N + 1) * 4;
    int*   cursor  = (int*)ws;   ws += (size_t)N * 4;
    int*   partial = (int*)ws;   ws += 256 * 4;
    int*   colsrc  = (int*)ws;   ws += (size_t)E * 4;

    int nb16 = (N + 15) / 16;
    int nbE  = (E + 255) / 256;
    int nblk = (N + 255) / 256;

    hipMemsetAsync(deg, 0, (size_t)N * 4, stream);
    k_xw  <<<nb16, 256, 0, stream>>>(x, W, att_src, att_dst, xp, a_src, a_dst, N);
    k_hist<<<nbE,  256, 0, stream>>>(dstIdx, deg, E);
    k_scan1<<<nblk, 256, 0, stream>>>(deg, row_ptr, partial, N);
    k_scan2<<<1,    256, 0, stream>>>(partial, nblk);
    k_scan3<<<nblk, 256, 0, stream>>>(deg, row_ptr, cursor, partial, N, E);
    k_fill<<<nbE,  256, 0, stream>>>(srcIdx, dstIdx, cursor, colsrc, E);
    k_agg <<<nb16, 256, 0, stream>>>(xp, a_src, a_dst, row_ptr, colsrc,
                                     bias, proj_w, proj_b, gamma, beta,
                                     (float*)d_out, N);
}